// Round 6
// baseline (283.915 us; speedup 1.0000x reference)
//
#include <hip/hip_runtime.h>
#include <math.h>

// QuantumIntegrator: r_embed [B=4, S=4096, 2] fp32, dt [4] fp32.
// Outputs (flat fp32): r_final [4,4096,2] then score [4,4096,4096].
//
// R9 theory: all five prior variants (274-292us) used row-per-wave score
// writing, which re-delivers ~512 B of operands per 1 KB store (L1 loads or
// 16-way-conflicted LDS reads: lane l -> lds byte 32l -> 4 distinct banks).
// Operand delivery (~55us/CU-serialized) matched the store floor (~41us) ->
// invariant ~100us. Fix: TRANSPOSE the assignment. Each wave owns a
// 256-column strip; lane's 4 columns' r-values live in 8 VGPRs (loaded
// once); per row the wave reads 12 wave-uniform bytes from LDS (broadcast,
// conflict-free, lgkmcnt) and issues one 1 KB store. vmcnt queue = stores
// only. Zero half of the triangle skips even the broadcast. Pass-2
// finalize = trailing heterogeneous blocks in the same dispatch.
// Prediction: dur 276 -> ~225-240. If >=270: operand path exonerated too
// -> harness roofline (fill 1.074GB + score 268MB = 209us mandatory HBM
// write + reduces/gaps), declare.

#define S_LEN 4096
#define ROWS  16384   // B*S with B=4 (fixed by setup_inputs)
#define BLK   256
#define EPSF  1e-6f
#define RATE  0.01f
#define MINR  0.1f
#define MAXR  2.0f

#define CB 16                     // 256-wide column blocks per batch
#define GB 8                      // row groups: 512 rows/block, 128/wave
#define SCORE_BLOCKS (4*CB*GB)    // 512
#define FIN_BLOCKS   (ROWS/4)     // 4096

// ws layout (floats):
//   [0,      2*ROWS) r_mid
//   [2*ROWS, 4*ROWS) k1
//   [4*ROWS, 5*ROWS) sum_score (D/dc)
//   [5*ROWS, 6*ROWS) inv (1/dc)

__global__ __launch_bounds__(BLK) void k_prep(
    const float2* __restrict__ r_in,
    const float*  __restrict__ dt_in,
    float* __restrict__ ws)
{
    const int lane = threadIdx.x & 63;
    const int row  = (blockIdx.x << 2) + (threadIdx.x >> 6);   // wave-per-row
    const int b = row >> 12;
    const int s = row & (S_LEN - 1);
    const float2* rb  = r_in + ((size_t)b << 12);
    const float4* rb4 = (const float4*)rb;        // one float4 = points (2i, 2i+1)
    const float2 rs = rb[s];

    float dsum = 0.f, nx = 0.f, ny = 0.f;
    for (int i = lane; 2*i <= s; i += 64) {
        float4 p = rb4[i];
        float d0 = fmaxf(rs.x * p.x + rs.y * p.y, 0.f);
        dsum += d0; nx = fmaf(d0, p.x, nx); ny = fmaf(d0, p.y, ny);
        if (2*i + 1 <= s) {
            float d1 = fmaxf(rs.x * p.z + rs.y * p.w, 0.f);
            dsum += d1; nx = fmaf(d1, p.z, nx); ny = fmaf(d1, p.w, ny);
        }
    }
    #pragma unroll
    for (int off = 32; off > 0; off >>= 1) {
        dsum += __shfl_down(dsum, off);
        nx   += __shfl_down(nx, off);
        ny   += __shfl_down(ny, off);
    }

    if (lane == 0) {
        const float D   = dsum;
        const float dc  = fmaxf(D, EPSF);
        const float dtb = dt_in[b];
        float k1x = dtb * nx / dc;
        float k1y = dtb * ny / dc;
        if (!isfinite(k1x)) k1x = 0.f;
        if (!isfinite(k1y)) k1y = 0.f;
        float rmx = rs.x + k1x, rmy = rs.y + k1y;
        if (!isfinite(rmx)) rmx = rs.x;
        if (!isfinite(rmy)) rmy = rs.y;
        ws[2*row]              = rmx;  ws[2*row + 1]          = rmy;  // r_mid
        ws[2*ROWS + 2*row]     = k1x;  ws[2*ROWS + 2*row + 1] = k1y;  // k1
        ws[4*ROWS + row]       = D / dc;       // row-sum of normalized score
        ws[5*ROWS + row]       = 1.f / dc;     // inv for the score writer
    }
}

// Heterogeneous dispatch: blocks [0,512) stream score (column-strip-per-wave,
// operands register-resident); blocks [512, 4608) finalize r_final.
__global__ __launch_bounds__(BLK) void k_main(
    const float2* __restrict__ r_in,
    const float*  __restrict__ dt_in,
    const float*  __restrict__ ws,
    float* __restrict__ score_out,                // fp32, [ROWS, S_LEN]
    float* __restrict__ rfinal_out)               // fp32, [ROWS, 2]
{
    __shared__ float2 lds_r[512];
    __shared__ float  lds_inv[512];

    const int wave = threadIdx.x >> 6;
    const int lane = threadIdx.x & 63;

    if (blockIdx.x < SCORE_BLOCKS) {
        // ---- score writer: wave owns cols [col0, col0+256) x rows [r0, r0+128)
        const int sb   = blockIdx.x;
        const int b    = sb >> 7;                 // / (CB*GB)
        const int rem  = sb & 127;
        const int c    = rem >> 3;                // column block
        const int g    = rem & 7;                 // row group
        const int col0 = c << 8;
        const int rbase= g << 9;                  // 512 rows per block

        const float4* rb4 = (const float4*)(r_in + ((size_t)b << 12));

        // Stage this block's 512 rows (rs, inv) into LDS once. 6 KB.
        ((float4*)lds_r)[threadIdx.x] = rb4[(rbase >> 1) + threadIdx.x];
        ((float2*)lds_inv)[threadIdx.x] =
            ((const float2*)(ws + 5*(size_t)ROWS + ((size_t)b << 12) + rbase))[threadIdx.x];

        // Lane's 4 columns, register-resident for the whole kernel.
        const float4 p01 = rb4[(col0 >> 1) + 2*lane];
        const float4 p23 = rb4[(col0 >> 1) + 2*lane + 1];
        __syncthreads();

        const int   t0g  = col0 + (lane << 2);    // global col of v.x
        const int   lr0  = wave << 7;             // local row base (128/wave)
        float* base = score_out
            + (size_t)(((size_t)b << 12) + rbase + lr0) * S_LEN + t0g;

        #pragma unroll 4
        for (int i = 0; i < 128; ++i) {
            const int lr = lr0 + i;
            const int r  = rbase + lr;            // row s within batch
            float4 v = make_float4(0.f, 0.f, 0.f, 0.f);
            if (r >= col0) {                      // wave-uniform; else strip is zero
                const float2 rs  = lds_r[lr];     // broadcast, conflict-free
                const float  inv = lds_inv[lr];
                const float isx = rs.x * inv, isy = rs.y * inv;
                const float a0 = fmaxf(isx * p01.x + isy * p01.y, 0.f);
                const float a1 = fmaxf(isx * p01.z + isy * p01.w, 0.f);
                const float a2 = fmaxf(isx * p23.x + isy * p23.y, 0.f);
                const float a3 = fmaxf(isx * p23.z + isy * p23.w, 0.f);
                v.x = (t0g     <= r) ? a0 : 0.f;
                v.y = (t0g + 1 <= r) ? a1 : 0.f;
                v.z = (t0g + 2 <= r) ? a2 : 0.f;
                v.w = (t0g + 3 <= r) ? a3 : 0.f;
            }
            *((float4*)(base + (size_t)i * S_LEN)) = v;   // 1 KB/wave, coalesced
        }
    } else {
        // ---- pass-2 finalize: wave-per-row triangular reduce on r_mid.
        const int row = ((blockIdx.x - SCORE_BLOCKS) << 2) + wave;
        const int b = row >> 12;
        const int s = row & (S_LEN - 1);
        const float4* rm4 = (const float4*)((const float2*)ws + ((size_t)b << 12));
        const float2  ms  = ((const float2*)ws)[((size_t)b << 12) + s];

        float dsum = 0.f, nx = 0.f, ny = 0.f;
        for (int i = lane; 2*i <= s; i += 64) {
            float4 p = rm4[i];
            float d0 = fmaxf(ms.x * p.x + ms.y * p.y, 0.f);
            dsum += d0; nx = fmaf(d0, p.x, nx); ny = fmaf(d0, p.y, ny);
            if (2*i + 1 <= s) {
                float d1 = fmaxf(ms.x * p.z + ms.y * p.w, 0.f);
                dsum += d1; nx = fmaf(d1, p.z, nx); ny = fmaf(d1, p.w, ny);
            }
        }
        #pragma unroll
        for (int off = 32; off > 0; off >>= 1) {
            dsum += __shfl_down(dsum, off);
            nx   += __shfl_down(nx, off);
            ny   += __shfl_down(ny, off);
        }

        if (lane == 0) {
            const float dc  = fmaxf(dsum, EPSF);
            const float dtb = dt_in[b];
            float k2x = dtb * nx / dc;
            float k2y = dtb * ny / dc;
            if (!isfinite(k2x)) k2x = 0.f;
            if (!isfinite(k2y)) k2y = 0.f;
            const float2 r0  = r_in[row];
            const float  k1x = ws[2*(size_t)ROWS + 2*row], k1y = ws[2*(size_t)ROWS + 2*row + 1];
            const float rnx = r0.x + 0.5f * (k1x + k2x);
            const float rny = r0.y + 0.5f * (k1y + k2y);
            const float nr  = fmaxf(sqrtf(rnx*rnx + rny*rny), EPSF);
            const float ar  = fminf(fmaxf(nr + ws[4*(size_t)ROWS + row] * RATE, MINR), MAXR);
            const float sc  = ar / nr;
            float fx = rnx * sc, fy = rny * sc;
            if (!isfinite(fx)) fx = r0.x;
            if (!isfinite(fy)) fy = r0.y;
            rfinal_out[2*row]     = fx;
            rfinal_out[2*row + 1] = fy;
        }
    }
}

extern "C" void kernel_launch(void* const* d_in, const int* in_sizes, int n_in,
                              void* d_out, int out_size, void* d_ws, size_t ws_size,
                              hipStream_t stream) {
    const float2* r_in  = (const float2*)d_in[0];   // fp32 [4,4096,2]
    const float*  dt_in = (const float*)d_in[1];    // fp32 [4]
    float* out = (float*)d_out;
    float* ws  = (float*)d_ws;

    // d_out: first ROWS*2 floats = r_final, then ROWS*S_LEN floats = score.
    float* rfinal_out = out;
    float* score_out  = out + (size_t)2 * ROWS;

    hipLaunchKernelGGL(k_prep, dim3(ROWS / 4), dim3(BLK), 0, stream,
                       r_in, dt_in, ws);
    hipLaunchKernelGGL(k_main, dim3(SCORE_BLOCKS + FIN_BLOCKS), dim3(BLK), 0, stream,
                       r_in, dt_in, ws, score_out, rfinal_out);
}